// Round 1
// baseline (245.652 us; speedup 1.0000x reference)
//
#include <hip/hip_runtime.h>

#define B 100
#define R 1152
#define C 10
#define O 16
#define I 8
#define RI 9216      // R*I
#define CO 160       // C*O
#define RCHUNK 32
#define NRC 36       // R / RCHUNK
#define KCH (RCHUNK*I)  // 256

// ws offsets (in floats)
#define WS_BCOL 0                  // 11520  b_ij stored [c][r]
#define WS_CSM  11520              // 11520  softmax c_ij stored [r][c]
#define WS_XT   23040              // 921600 + 128 pad: xT[k][b], k=r*8+i
#define WS_PART 944768             // 10*36*100*16 = 576000 partial s_j
#define WS_V    1520768            // 16000  v_j [b][c][o]
#define WS_SMUT 1536768            // 16000  s_mut [b][c][o]
// total: 1,552,768 floats = 6.22 MB

// ---------- init: transpose x0 -> xT, zero b_ij ----------
__global__ void k_init(const float* __restrict__ x0, float* __restrict__ ws) {
    int idx = blockIdx.x * 256 + threadIdx.x;   // 3600 blocks * 256 = 921600
    if (idx < RI * B) {
        int k = idx / B;
        int b = idx - k * B;
        ws[WS_XT + idx] = x0[b * RI + k];
    }
    if (idx < R * C) ws[WS_BCOL + idx] = 0.f;
}

// ---------- GEMM1: partial s_j, softmax fused; blocks (rc=36, c=10) ----------
__global__ __launch_bounds__(256) void k_gemm1(const float* __restrict__ Wg,
                                               float* __restrict__ ws) {
    const int rc = blockIdx.x, c = blockIdx.y;
    const int t = threadIdx.x;
    const int r0 = rc * RCHUNK;
    __shared__ float red[256];
    __shared__ float cw[RCHUNK];
    __shared__ float lw[KCH * O];   // 4096 floats: [k][o], c-weight folded
    const float* bcol = ws + WS_BCOL + c * R;

    // softmax over r (all blocks for class c compute it redundantly; cheap)
    float lm = -3.4e38f;
    for (int r = t; r < R; r += 256) lm = fmaxf(lm, bcol[r]);
    red[t] = lm; __syncthreads();
    for (int s = 128; s > 0; s >>= 1) { if (t < s) red[t] = fmaxf(red[t], red[t + s]); __syncthreads(); }
    const float m = red[0]; __syncthreads();
    float ls = 0.f;
    for (int r = t; r < R; r += 256) ls += expf(bcol[r] - m);
    red[t] = ls; __syncthreads();
    for (int s = 128; s > 0; s >>= 1) { if (t < s) red[t] += red[t + s]; __syncthreads(); }
    const float sinv = 1.f / red[0];
    if (t < RCHUNK) {
        float w_ = expf(bcol[r0 + t] - m) * sinv;
        cw[t] = w_;
        ws[WS_CSM + (r0 + t) * C + c] = w_;   // final iteration leaves c_full source
    }
    __syncthreads();

    // stage c-weighted W slice into LDS: lw[(rr*8+i)*16+o] = cw[rr]*W[r0+rr,c,o,i]
    for (int j = t; j < KCH * O; j += 256) {
        int rr = j >> 7;          // /128
        int rem = j & 127;        // o*8+i
        int o = rem >> 3, i = rem & 7;
        lw[(rr * I + i) * O + o] = cw[rr] * Wg[((size_t)(r0 + rr) * C + c) * (O * I) + rem];
    }
    __syncthreads();

    // compute: thread = (b-lane 0..63, o-group 0..3); 2 b's x 4 o's per thread
    const int bl = t & 63, og = t >> 6;
    const float* xT = ws + WS_XT + (r0 * I) * B + bl;
    const float4* lw4 = (const float4*)lw;
    float4 a0 = {0, 0, 0, 0}, a1 = {0, 0, 0, 0};
    #pragma unroll 8
    for (int k = 0; k < KCH; k++) {
        float xv0 = xT[0];
        float xv1 = xT[64];       // pad at end of xT makes this safe; discarded if b>=100
        float4 wv = lw4[k * 4 + og];
        a0.x += xv0 * wv.x; a0.y += xv0 * wv.y; a0.z += xv0 * wv.z; a0.w += xv0 * wv.w;
        a1.x += xv1 * wv.x; a1.y += xv1 * wv.y; a1.z += xv1 * wv.z; a1.w += xv1 * wv.w;
        xT += B;
    }
    float4* part4 = (float4*)(ws + WS_PART);
    int base = ((c * NRC + rc) * B + bl) * 4 + og;
    part4[base] = a0;
    if (bl < B - 64) part4[base + 64 * 4] = a1;
}

// ---------- reduce partials + squash; one block per b ----------
__global__ __launch_bounds__(256) void k_squash(float* __restrict__ ws) {
    const int b = blockIdx.x, t = threadIdx.x;
    __shared__ float sl[CO];
    __shared__ float nf[C];
    if (t < CO) {
        int c = t >> 4, o = t & 15;
        float s = 0.f;
        const float* p = ws + WS_PART + ((size_t)c * NRC * B + b) * 16 + o;
        #pragma unroll
        for (int rc = 0; rc < NRC; rc++) s += p[(size_t)rc * B * 16];
        sl[t] = s;
    }
    __syncthreads();
    if (t < C) {
        float fv[C];
        #pragma unroll
        for (int c2 = 0; c2 < C; c2++) fv[c2] = sl[c2 * O];
        float mine = sl[t * O];
        int rank = 0, i1 = 0, i2 = 0, i3 = 0;
        #pragma unroll
        for (int c2 = 0; c2 < C; c2++) {
            rank += (fv[c2] < mine) || (fv[c2] == mine && c2 < t);
            i1 += fv[c2] < -0.075410217f;
            i2 += fv[c2] < 0.0f;
            i3 += fv[c2] < 0.062207676f;
        }
        float nv = mine;
        if (i1 > 0 && rank < i1 - 1)                               nv = -0.074520095f * mine + 0.349297946f;
        else if (i2 > 0 && i2 > i1 && rank >= i1 && rank < i2 - 1) nv = -0.534473989f * mine + 0.27196494f;
        else if (i3 > 0 && i3 > i2 && rank >= i2 && rank < i3 - 1) nv = 0.637642944f * mine + 0.295330779f;
        else if (i3 < C && rank >= i3 && rank < C - 1)             nv = 0.169344703f * mine + 0.353784456f;
        nf[t] = nv;
    }
    __syncthreads();
    if (t < CO) {
        int c = t >> 4, o = t & 15;
        float sv = sl[t];
        float nfv = nf[c];
        float smut = (o == 0) ? nfv : sv;
        ws[WS_SMUT + b * CO + t] = smut;
        ws[WS_V + b * CO + t] = nfv * smut;
    }
}

// ---------- agreement: b_ij += mean_b sum_o u_hat*v ; one block per r ----------
__global__ __launch_bounds__(256) void k_agree(const float* __restrict__ Wg,
                                               float* __restrict__ ws) {
    const int r = blockIdx.x, t = threadIdx.x;
    __shared__ float vt[32 * B];   // [cc][b] for one co-chunk
    __shared__ float xs[I * B];    // [i][b]
    __shared__ float arr[CO * I];  // products W*q, grouped by c (128 per c)
    for (int j = t; j < I * B; j += 256) xs[j] = ws[WS_XT + (size_t)r * I * B + j];
    const int i = t & 7, co0 = t >> 3;
    const float4* xs4 = (const float4*)(xs + i * B);
    const float4* vt4 = (const float4*)(vt + co0 * B);
    for (int ch = 0; ch < 5; ch++) {
        __syncthreads();   // protects vt overwrite; first pass also covers xs writes
        for (int j = t; j < 32 * B; j += 256) {
            int b = j >> 5, cc = j & 31;
            vt[cc * B + b] = ws[WS_V + b * CO + ch * 32 + cc];
        }
        __syncthreads();
        float q = 0.f;
        #pragma unroll
        for (int b4 = 0; b4 < B / 4; b4++) {
            float4 xv = xs4[b4];
            float4 vv = vt4[b4];
            q += xv.x * vv.x + xv.y * vv.y + xv.z * vv.z + xv.w * vv.w;
        }
        int co = ch * 32 + co0;
        arr[co * I + i] = q * Wg[(size_t)r * (C * O * I) + co * I + i];
    }
    __syncthreads();
    if (t < C) {
        const float4* a4 = (const float4*)(arr + t * 128);
        float d = 0.f;
        #pragma unroll
        for (int m2 = 0; m2 < 32; m2++) { float4 v4 = a4[m2]; d += v4.x + v4.y + v4.z + v4.w; }
        ws[WS_BCOL + t * R + r] += d * (1.0f / B);
    }
}

// ---------- Wb broadcast: read W once, write 100x from registers ----------
__global__ void k_wb(const float* __restrict__ Wg, float4* __restrict__ out) {
    int idx = blockIdx.x * 256 + threadIdx.x;        // 1440*256 = 368640 f4 = W size
    float4 v = ((const float4*)Wg)[idx];
    float4* dst = out + 292000 + idx;
    #pragma unroll 4
    for (int b = 0; b < B; b++) { *dst = v; dst += 368640; }
}

// ---------- remaining outputs, fused float4 grid-stride ----------
// segment f4 offsets: v_j 0..4000 | c_full 4000..292000 | (Wb 292000..37156000 done)
// squashed_u 37156000..39460000 | x1 ..39690400 | x2 ..39710000 | s_mut ..39714000
__global__ void k_out(const float* __restrict__ x0, const float* __restrict__ x1,
                      const float* __restrict__ x2, const float* __restrict__ ws,
                      float4* __restrict__ out) {
    const float4* x04 = (const float4*)x0;
    const float4* x14 = (const float4*)x1;
    const float4* x24 = (const float4*)x2;
    const float4* v4  = (const float4*)(ws + WS_V);
    const float4* sm4 = (const float4*)(ws + WS_SMUT);
    const float4* cs4 = (const float4*)(ws + WS_CSM);
    const int stride = gridDim.x * blockDim.x;
    for (int u = blockIdx.x * blockDim.x + threadIdx.x; u < 2850000; u += stride) {
        int g = (u < 292000) ? u : u + 36864000;   // skip the Wb region
        float4 val;
        if (g >= 37156000 && g < 39460000) {        // squashed_u: x0 bcast over c
            int j = g - 37156000;
            int br = j / 20;
            val = x04[br * 2 + (j & 1)];
        } else if (g >= 4000 && g < 292000) {       // c_full: csm repeated per b
            int j = g - 4000;
            val = cs4[j % 2880];
        } else if (g < 4000) {                      // v_j
            val = v4[g];
        } else if (g < 39690400) {                  // x1 copy
            val = x14[g - 39460000];
        } else if (g < 39710000) {                  // x2 copy
            val = x24[g - 39690400];
        } else {                                    // s_mut
            val = sm4[g - 39710000];
        }
        out[g] = val;
    }
}

extern "C" void kernel_launch(void* const* d_in, const int* in_sizes, int n_in,
                              void* d_out, int out_size, void* d_ws, size_t ws_size,
                              hipStream_t stream) {
    (void)in_sizes; (void)n_in; (void)out_size; (void)ws_size;
    const float* x0 = (const float*)d_in[0];
    const float* x1 = (const float*)d_in[1];
    const float* x2 = (const float*)d_in[2];
    const float* Wg = (const float*)d_in[3];
    float* ws = (float*)d_ws;
    float4* out = (float4*)d_out;

    hipLaunchKernelGGL(k_init, dim3(3600), dim3(256), 0, stream, x0, ws);
    for (int it = 0; it < 3; it++) {
        hipLaunchKernelGGL(k_gemm1, dim3(NRC, C), dim3(256), 0, stream, Wg, ws);
        hipLaunchKernelGGL(k_squash, dim3(B), dim3(256), 0, stream, ws);
        if (it < 2)
            hipLaunchKernelGGL(k_agree, dim3(R), dim3(256), 0, stream, Wg, ws);
    }
    hipLaunchKernelGGL(k_wb, dim3(1440), dim3(256), 0, stream, Wg, out);
    hipLaunchKernelGGL(k_out, dim3(2048), dim3(256), 0, stream, x0, x1, x2, ws, out);
}

// Round 3
// 234.833 us; speedup vs baseline: 1.0461x; 1.0461x over previous
//
#include <hip/hip_runtime.h>

#define B 100
#define R 1152
#define C 10
#define O 16
#define I 8
#define RI 9216      // R*I
#define CO 160       // C*O
#define RCHUNK 32
#define NRC 36       // R / RCHUNK
#define KCH (RCHUNK*I)  // 256

typedef float f4raw __attribute__((ext_vector_type(4)));
__device__ __forceinline__ void nt_store4(const float4& v, float4* p) {
    __builtin_nontemporal_store(*(const f4raw*)&v, (f4raw*)p);
}

// ws offsets (in floats)
#define WS_BCOL 0                  // 11520  b_ij stored [c][r]
#define WS_CSM  11520              // 11520  softmax c_ij stored [r][c]
#define WS_XT   23040              // 921600 + 128 pad: xT[k][b], k=r*8+i
#define WS_PART 944768             // 10*36*100*16 = 576000 partial s_j
#define WS_V    1520768            // 16000  v_j [b][c][o]
#define WS_SMUT 1536768            // 16000  s_mut [b][c][o]
// total: 1,552,768 floats = 6.22 MB

// ---- Wb broadcast work units: unit = (bgroup 0..4, wchunk 0..1439) ----
// each unit: 256 threads each own one W float4, store it to 20 b's (80 KB).
#define WB_OUT_BASE 292000
#define WB_WSTRIDE  368640
#define WB_NCHUNK   1440
#define WB_BG       20
#define WB_UNITS    7200

__device__ __forceinline__ void wb_unit(const float4* __restrict__ W4,
                                        float4* __restrict__ out, int unit) {
    int wchunk = unit % WB_NCHUNK;
    int bg = unit / WB_NCHUNK;
    int idx = wchunk * 256 + threadIdx.x;
    float4 v = W4[idx];
    float4* dst = out + WB_OUT_BASE + (size_t)bg * WB_BG * WB_WSTRIDE + idx;
    #pragma unroll
    for (int b = 0; b < WB_BG; b++) {
        nt_store4(v, dst);
        dst += WB_WSTRIDE;
    }
}

// ---------- init: transpose x0 -> xT, zero b_ij; + Wb slice ----------
__global__ void k_init(const float* __restrict__ x0, float* __restrict__ ws,
                       const float4* __restrict__ W4, float4* __restrict__ out) {
    if (blockIdx.x >= 3600) { wb_unit(W4, out, 0 + (blockIdx.x - 3600)); return; }
    int idx = blockIdx.x * 256 + threadIdx.x;   // 3600 blocks * 256 = 921600
    if (idx < RI * B) {
        int k = idx / B;
        int b = idx - k * B;
        ws[WS_XT + idx] = x0[b * RI + k];
    }
    if (idx < R * C) ws[WS_BCOL + idx] = 0.f;
}

// ---------- GEMM1: partial s_j, softmax fused; blocks (rc=36 + 90 wb, c=10) ----------
__global__ __launch_bounds__(256) void k_gemm1(const float* __restrict__ Wg,
                                               float* __restrict__ ws,
                                               float4* __restrict__ out, int wbBase) {
    if (blockIdx.x >= NRC) {
        wb_unit((const float4*)Wg, out, wbBase + (blockIdx.x - NRC) + 90 * blockIdx.y);
        return;
    }
    const int rc = blockIdx.x, c = blockIdx.y;
    const int t = threadIdx.x;
    const int r0 = rc * RCHUNK;
    __shared__ float red[256];
    __shared__ float cw[RCHUNK];
    __shared__ float lw[KCH * O];   // 4096 floats: [k][o], c-weight folded
    const float* bcol = ws + WS_BCOL + c * R;

    // softmax over r (all blocks for class c compute it redundantly; cheap)
    float lm = -3.4e38f;
    for (int r = t; r < R; r += 256) lm = fmaxf(lm, bcol[r]);
    red[t] = lm; __syncthreads();
    for (int s = 128; s > 0; s >>= 1) { if (t < s) red[t] = fmaxf(red[t], red[t + s]); __syncthreads(); }
    const float m = red[0]; __syncthreads();
    float ls = 0.f;
    for (int r = t; r < R; r += 256) ls += expf(bcol[r] - m);
    red[t] = ls; __syncthreads();
    for (int s = 128; s > 0; s >>= 1) { if (t < s) red[t] += red[t + s]; __syncthreads(); }
    const float sinv = 1.f / red[0];
    if (t < RCHUNK) {
        float w_ = expf(bcol[r0 + t] - m) * sinv;
        cw[t] = w_;
        ws[WS_CSM + (r0 + t) * C + c] = w_;   // final iteration leaves c_full source
    }
    __syncthreads();

    // stage c-weighted W slice into LDS: lw[(rr*8+i)*16+o] = cw[rr]*W[r0+rr,c,o,i]
    for (int j = t; j < KCH * O; j += 256) {
        int rr = j >> 7;          // /128
        int rem = j & 127;        // o*8+i
        int o = rem >> 3, i = rem & 7;
        lw[(rr * I + i) * O + o] = cw[rr] * Wg[((size_t)(r0 + rr) * C + c) * (O * I) + rem];
    }
    __syncthreads();

    // compute: thread = (b-lane 0..63, o-group 0..3); 2 b's x 4 o's per thread
    const int bl = t & 63, og = t >> 6;
    const float* xT = ws + WS_XT + (r0 * I) * B + bl;
    const float4* lw4 = (const float4*)lw;
    float4 a0 = {0, 0, 0, 0}, a1 = {0, 0, 0, 0};
    #pragma unroll 8
    for (int k = 0; k < KCH; k++) {
        float xv0 = xT[0];
        float xv1 = xT[64];       // pad at end of xT makes this safe; discarded if b>=100
        float4 wv = lw4[k * 4 + og];
        a0.x += xv0 * wv.x; a0.y += xv0 * wv.y; a0.z += xv0 * wv.z; a0.w += xv0 * wv.w;
        a1.x += xv1 * wv.x; a1.y += xv1 * wv.y; a1.z += xv1 * wv.z; a1.w += xv1 * wv.w;
        xT += B;
    }
    float4* part4 = (float4*)(ws + WS_PART);
    int base = ((c * NRC + rc) * B + bl) * 4 + og;
    part4[base] = a0;
    if (bl < B - 64) part4[base + 64 * 4] = a1;
}

// ---------- reduce partials + squash; one block per b; + Wb slice ----------
__global__ __launch_bounds__(256) void k_squash(float* __restrict__ ws,
                                                const float4* __restrict__ W4,
                                                float4* __restrict__ out, int wbBase) {
    if (blockIdx.x >= B) { wb_unit(W4, out, wbBase + (blockIdx.x - B)); return; }
    const int b = blockIdx.x, t = threadIdx.x;
    __shared__ float sl[CO];
    __shared__ float nf[C];
    if (t < CO) {
        int c = t >> 4, o = t & 15;
        float s = 0.f;
        const float* p = ws + WS_PART + ((size_t)c * NRC * B + b) * 16 + o;
        #pragma unroll
        for (int rc = 0; rc < NRC; rc++) s += p[(size_t)rc * B * 16];
        sl[t] = s;
    }
    __syncthreads();
    if (t < C) {
        float fv[C];
        #pragma unroll
        for (int c2 = 0; c2 < C; c2++) fv[c2] = sl[c2 * O];
        float mine = sl[t * O];
        int rank = 0, i1 = 0, i2 = 0, i3 = 0;
        #pragma unroll
        for (int c2 = 0; c2 < C; c2++) {
            rank += (fv[c2] < mine) || (fv[c2] == mine && c2 < t);
            i1 += fv[c2] < -0.075410217f;
            i2 += fv[c2] < 0.0f;
            i3 += fv[c2] < 0.062207676f;
        }
        float nv = mine;
        if (i1 > 0 && rank < i1 - 1)                               nv = -0.074520095f * mine + 0.349297946f;
        else if (i2 > 0 && i2 > i1 && rank >= i1 && rank < i2 - 1) nv = -0.534473989f * mine + 0.27196494f;
        else if (i3 > 0 && i3 > i2 && rank >= i2 && rank < i3 - 1) nv = 0.637642944f * mine + 0.295330779f;
        else if (i3 < C && rank >= i3 && rank < C - 1)             nv = 0.169344703f * mine + 0.353784456f;
        nf[t] = nv;
    }
    __syncthreads();
    if (t < CO) {
        int c = t >> 4, o = t & 15;
        float sv = sl[t];
        float nfv = nf[c];
        float smut = (o == 0) ? nfv : sv;
        ws[WS_SMUT + b * CO + t] = smut;
        ws[WS_V + b * CO + t] = nfv * smut;
    }
}

// ---------- agreement: b_ij += mean_b sum_o u_hat*v ; one block per r; + Wb slice ----------
__global__ __launch_bounds__(256) void k_agree(const float* __restrict__ Wg,
                                               float* __restrict__ ws,
                                               float4* __restrict__ out, int wbBase) {
    if (blockIdx.x >= R) { wb_unit((const float4*)Wg, out, wbBase + (blockIdx.x - R)); return; }
    const int r = blockIdx.x, t = threadIdx.x;
    __shared__ float vt[32 * B];   // [cc][b] for one co-chunk
    __shared__ float xs[I * B];    // [i][b]
    __shared__ float arr[CO * I];  // products W*q, grouped by c (128 per c)
    for (int j = t; j < I * B; j += 256) xs[j] = ws[WS_XT + (size_t)r * I * B + j];
    const int i = t & 7, co0 = t >> 3;
    const float4* xs4 = (const float4*)(xs + i * B);
    const float4* vt4 = (const float4*)(vt + co0 * B);
    for (int ch = 0; ch < 5; ch++) {
        __syncthreads();   // protects vt overwrite; first pass also covers xs writes
        for (int j = t; j < 32 * B; j += 256) {
            int b = j >> 5, cc = j & 31;
            vt[cc * B + b] = ws[WS_V + b * CO + ch * 32 + cc];
        }
        __syncthreads();
        float q = 0.f;
        #pragma unroll
        for (int b4 = 0; b4 < B / 4; b4++) {
            float4 xv = xs4[b4];
            float4 vv = vt4[b4];
            q += xv.x * vv.x + xv.y * vv.y + xv.z * vv.z + xv.w * vv.w;
        }
        int co = ch * 32 + co0;
        arr[co * I + i] = q * Wg[(size_t)r * (C * O * I) + co * I + i];
    }
    __syncthreads();
    if (t < C) {
        const float4* a4 = (const float4*)(arr + t * 128);
        float d = 0.f;
        #pragma unroll
        for (int m2 = 0; m2 < 32; m2++) { float4 v4 = a4[m2]; d += v4.x + v4.y + v4.z + v4.w; }
        ws[WS_BCOL + t * R + r] += d * (1.0f / B);
    }
}

// ---------- remaining outputs, fused float4 grid-stride; + Wb slice ----------
// segment f4 offsets: v_j 0..4000 | c_full 4000..292000 | (Wb 292000..37156000 sliced)
// squashed_u 37156000..39460000 | x1 ..39690400 | x2 ..39710000 | s_mut ..39714000
#define KOUT_BLOCKS 2048
__global__ void k_out(const float* __restrict__ x0, const float* __restrict__ x1,
                      const float* __restrict__ x2, const float* __restrict__ ws,
                      const float4* __restrict__ W4, float4* __restrict__ out,
                      int wbBase) {
    if (blockIdx.x >= KOUT_BLOCKS) { wb_unit(W4, out, wbBase + (blockIdx.x - KOUT_BLOCKS)); return; }
    const float4* x04 = (const float4*)x0;
    const float4* x14 = (const float4*)x1;
    const float4* x24 = (const float4*)x2;
    const float4* v4  = (const float4*)(ws + WS_V);
    const float4* sm4 = (const float4*)(ws + WS_SMUT);
    const float4* cs4 = (const float4*)(ws + WS_CSM);
    const int stride = KOUT_BLOCKS * 256;
    for (int u = blockIdx.x * 256 + threadIdx.x; u < 2850000; u += stride) {
        int g = (u < 292000) ? u : u + 36864000;   // skip the Wb region
        float4 val;
        if (g >= 37156000 && g < 39460000) {        // squashed_u: x0 bcast over c
            int j = g - 37156000;
            int br = j / 20;
            val = x04[br * 2 + (j & 1)];
        } else if (g >= 4000 && g < 292000) {       // c_full: csm repeated per b
            int j = g - 4000;
            val = cs4[j % 2880];
        } else if (g < 4000) {                      // v_j
            val = v4[g];
        } else if (g < 39690400) {                  // x1 copy
            val = x14[g - 39460000];
        } else if (g < 39710000) {                  // x2 copy
            val = x24[g - 39690400];
        } else {                                    // s_mut
            val = sm4[g - 39710000];
        }
        nt_store4(val, &out[g]);
    }
}

extern "C" void kernel_launch(void* const* d_in, const int* in_sizes, int n_in,
                              void* d_out, int out_size, void* d_ws, size_t ws_size,
                              hipStream_t stream) {
    (void)in_sizes; (void)n_in; (void)out_size; (void)ws_size;
    const float* x0 = (const float*)d_in[0];
    const float* x1 = (const float*)d_in[1];
    const float* x2 = (const float*)d_in[2];
    const float* Wg = (const float*)d_in[3];
    const float4* W4 = (const float4*)Wg;
    float* ws = (float*)d_ws;
    float4* out = (float4*)d_out;

    // Wb slice bases (7200 units total):
    // init 0..600 | gemm1 it: 600+900*it | squash it: 3300+500*it |
    // agree it: 4800+700*it | out: 6200..7200
    hipLaunchKernelGGL(k_init, dim3(3600 + 600), dim3(256), 0, stream, x0, ws, W4, out);
    for (int it = 0; it < 3; it++) {
        hipLaunchKernelGGL(k_gemm1, dim3(NRC + 90, C), dim3(256), 0, stream,
                           Wg, ws, out, 600 + 900 * it);
        hipLaunchKernelGGL(k_squash, dim3(B + 500), dim3(256), 0, stream,
                           ws, W4, out, 3300 + 500 * it);
        if (it < 2)
            hipLaunchKernelGGL(k_agree, dim3(R + 700), dim3(256), 0, stream,
                               Wg, ws, out, 4800 + 700 * it);
    }
    hipLaunchKernelGGL(k_out, dim3(KOUT_BLOCKS + 1000), dim3(256), 0, stream,
                       x0, x1, x2, ws, W4, out, 6200);
}